// Round 1
// baseline (2249.036 us; speedup 1.0000x reference)
//
#include <hip/hip_runtime.h>
#include <math.h>

#define D_MODEL 1024
#define NH      16
#define DH      64
#define S_LEN   2048
#define BATCH   4

// ---------------------------------------------------------------------------
// Kernel 0: precise RoPE table  tab[0:65536) = cos, tab[65536:131072) = sin
// indexed by s*32 + p  (p = pair index 0..31)
// ---------------------------------------------------------------------------
__global__ void rope_table_kernel(float* __restrict__ tab) {
  int i = blockIdx.x * 256 + threadIdx.x;       // 0 .. 65535
  if (i >= S_LEN * 32) return;
  int s = i >> 5;
  int p = i & 31;
  // inv_freq = 10000^(-p/32) ; compute in double, round to fp32 (matches ref ~1ulp)
  float invf = (float)pow(10000.0, -(double)p / 32.0);
  float ang = (float)s * invf;                  // fp32 rounding, like reference
  tab[i]          = cosf(ang);                  // precise device libm (full reduction)
  tab[65536 + i]  = sinf(ang);
}

// ---------------------------------------------------------------------------
// GEMM  C[M,N] = A[M,K] * B[N,K]^T    (both operands K-contiguous)
// BM=BN=64, BK=16, 256 threads, 4x4 per thread.
// MODE 0: plain store to C.
// MODE 1: QKV epilogue -> apply RoPE to q,k and scatter to [b,h,s,d] buffers.
// ---------------------------------------------------------------------------
template <int MODE>
__global__ __launch_bounds__(256) void gemm_bt(
    const float* __restrict__ A, const float* __restrict__ B,
    float* __restrict__ C,
    float* __restrict__ qw, float* __restrict__ kw, float* __restrict__ vw,
    const float* __restrict__ tab,
    int M, int N, int K)
{
  __shared__ float As[16][64];   // [k][m] transposed
  __shared__ float Bs[16][64];   // [k][n] transposed

  const int tid = threadIdx.x;
  const int ty = tid >> 4;        // 0..15
  const int tx = tid & 15;        // 0..15
  const int m0 = blockIdx.y * 64;
  const int n0 = blockIdx.x * 64;

  const int lrow = tid >> 2;            // 0..63
  const int lk4  = (tid & 3) * 4;       // 0,4,8,12

  float acc[4][4] = {{0.f}};

  for (int k0 = 0; k0 < K; k0 += 16) {
    float4 av = *reinterpret_cast<const float4*>(&A[(size_t)(m0 + lrow) * K + k0 + lk4]);
    float4 bv = *reinterpret_cast<const float4*>(&B[(size_t)(n0 + lrow) * K + k0 + lk4]);
    __syncthreads();   // previous iteration finished reading LDS
    As[lk4 + 0][lrow] = av.x; As[lk4 + 1][lrow] = av.y;
    As[lk4 + 2][lrow] = av.z; As[lk4 + 3][lrow] = av.w;
    Bs[lk4 + 0][lrow] = bv.x; Bs[lk4 + 1][lrow] = bv.y;
    Bs[lk4 + 2][lrow] = bv.z; Bs[lk4 + 3][lrow] = bv.w;
    __syncthreads();
#pragma unroll
    for (int kk = 0; kk < 16; ++kk) {
      float4 a = *reinterpret_cast<const float4*>(&As[kk][ty * 4]);
      float4 b = *reinterpret_cast<const float4*>(&Bs[kk][tx * 4]);
      acc[0][0] += a.x * b.x; acc[0][1] += a.x * b.y; acc[0][2] += a.x * b.z; acc[0][3] += a.x * b.w;
      acc[1][0] += a.y * b.x; acc[1][1] += a.y * b.y; acc[1][2] += a.y * b.z; acc[1][3] += a.y * b.w;
      acc[2][0] += a.z * b.x; acc[2][1] += a.z * b.y; acc[2][2] += a.z * b.z; acc[2][3] += a.z * b.w;
      acc[3][0] += a.w * b.x; acc[3][1] += a.w * b.y; acc[3][2] += a.w * b.z; acc[3][3] += a.w * b.w;
    }
  }

  if (MODE == 0) {
#pragma unroll
    for (int i = 0; i < 4; ++i) {
      int m = m0 + ty * 4 + i;
      float4 o = make_float4(acc[i][0], acc[i][1], acc[i][2], acc[i][3]);
      *reinterpret_cast<float4*>(&C[(size_t)m * N + n0 + tx * 4]) = o;
    }
  } else {
    // e = n0 + tx*4 + j ; whole block shares t and h since 64 | n0
    const int t = n0 >> 10;                // 0=q 1=k 2=v
    const int h = (n0 & 1023) >> 6;        // head
    // d = tx*4 + j (n0 % 64 == 0)
#pragma unroll
    for (int i = 0; i < 4; ++i) {
      int m = m0 + ty * 4 + i;
      int b = m >> 11;                     // / 2048
      int s = m & 2047;
      size_t off = ((size_t)(b * NH + h) * S_LEN + s) * DH + tx * 4;
      if (t == 2) {
        float4 o = make_float4(acc[i][0], acc[i][1], acc[i][2], acc[i][3]);
        *reinterpret_cast<float4*>(&vw[off]) = o;
      } else {
        int p0 = tx * 2, p1 = tx * 2 + 1;
        float c0 = tab[s * 32 + p0], s0 = tab[65536 + s * 32 + p0];
        float c1 = tab[s * 32 + p1], s1 = tab[65536 + s * 32 + p1];
        float4 o;
        o.x = acc[i][0] * c0 - acc[i][1] * s0;
        o.y = acc[i][0] * s0 + acc[i][1] * c0;
        o.z = acc[i][2] * c1 - acc[i][3] * s1;
        o.w = acc[i][2] * s1 + acc[i][3] * c1;
        float* dst = (t == 0) ? qw : kw;
        *reinterpret_cast<float4*>(&dst[off]) = o;
      }
    }
  }
}

// ---------------------------------------------------------------------------
// Flash-style causal attention. One block per (q-tile of 64 rows, b*h).
// QBLK = KBLK = 64, 256 threads, 4x4 per-thread tiles.
// q/k/v in [b*h][s][64] layout; output scattered to [b][s][h*64+d].
// ---------------------------------------------------------------------------
__global__ __launch_bounds__(256) void attn_kernel(
    const float* __restrict__ qw, const float* __restrict__ kw,
    const float* __restrict__ vw, float* __restrict__ ow)
{
  __shared__ float QsT[64][68];    // [d][r]
  __shared__ float KPsT[64][68];   // K: [d][c]  then reused as P^T: [c][r]
  __shared__ float Vs[64][64];     // [c][d]

  const int tid = threadIdx.x;
  const int ty = tid >> 4, tx = tid & 15;
  const int qt = blockIdx.x;            // q tile 0..31
  const int bh = blockIdx.y;            // 0..63
  const int q0 = qt * 64;
  const size_t base = (size_t)bh * S_LEN * DH;

  // load Q tile transposed
  for (int it = tid; it < 64 * 16; it += 256) {
    int r = it >> 4, c4 = (it & 15) * 4;
    float4 v = *reinterpret_cast<const float4*>(&qw[base + (size_t)(q0 + r) * DH + c4]);
    QsT[c4 + 0][r] = v.x; QsT[c4 + 1][r] = v.y;
    QsT[c4 + 2][r] = v.z; QsT[c4 + 3][r] = v.w;
  }

  const int r0 = ty * 4, c0 = tx * 4;
  const float scale = 0.125f;

  float m_run[4] = {-3.0e38f, -3.0e38f, -3.0e38f, -3.0e38f};
  float l_run[4] = {0.f, 0.f, 0.f, 0.f};
  float o[4][4] = {{0.f}};

  for (int kt = 0; kt <= qt; ++kt) {
    const int k0 = kt * 64;
    __syncthreads();   // prev PV done reading KPsT/Vs (also covers Q stores, iter 0)

    // load K transposed + V natural
    for (int it = tid; it < 64 * 16; it += 256) {
      int r = it >> 4, c4 = (it & 15) * 4;
      float4 kv = *reinterpret_cast<const float4*>(&kw[base + (size_t)(k0 + r) * DH + c4]);
      KPsT[c4 + 0][r] = kv.x; KPsT[c4 + 1][r] = kv.y;
      KPsT[c4 + 2][r] = kv.z; KPsT[c4 + 3][r] = kv.w;
      float4 vv = *reinterpret_cast<const float4*>(&vw[base + (size_t)(k0 + r) * DH + c4]);
      *reinterpret_cast<float4*>(&Vs[r][c4]) = vv;
    }
    __syncthreads();

    // S = scale * Q K^T
    float sc[4][4] = {{0.f}};
#pragma unroll
    for (int kk = 0; kk < 64; ++kk) {
      float4 a = *reinterpret_cast<const float4*>(&QsT[kk][r0]);
      float4 b = *reinterpret_cast<const float4*>(&KPsT[kk][c0]);
      sc[0][0] += a.x * b.x; sc[0][1] += a.x * b.y; sc[0][2] += a.x * b.z; sc[0][3] += a.x * b.w;
      sc[1][0] += a.y * b.x; sc[1][1] += a.y * b.y; sc[1][2] += a.y * b.z; sc[1][3] += a.y * b.w;
      sc[2][0] += a.z * b.x; sc[2][1] += a.z * b.y; sc[2][2] += a.z * b.z; sc[2][3] += a.z * b.w;
      sc[3][0] += a.w * b.x; sc[3][1] += a.w * b.y; sc[3][2] += a.w * b.z; sc[3][3] += a.w * b.w;
    }

    const bool diag = (kt == qt);
    float p[4][4];
#pragma unroll
    for (int i = 0; i < 4; ++i) {
#pragma unroll
      for (int j = 0; j < 4; ++j) {
        float v = sc[i][j] * scale;
        if (diag && (c0 + j) > (r0 + i)) v = -3.0e38f;
        sc[i][j] = v;
      }
      // row max across this thread's 4 + the 16 threads sharing the row group
      float mx = fmaxf(fmaxf(sc[i][0], sc[i][1]), fmaxf(sc[i][2], sc[i][3]));
#pragma unroll
      for (int off = 1; off < 16; off <<= 1) mx = fmaxf(mx, __shfl_xor(mx, off, 64));
      float mnew = fmaxf(m_run[i], mx);
      float alpha = __expf(m_run[i] - mnew);
      float rs = 0.f;
#pragma unroll
      for (int j = 0; j < 4; ++j) { p[i][j] = __expf(sc[i][j] - mnew); rs += p[i][j]; }
#pragma unroll
      for (int off = 1; off < 16; off <<= 1) rs += __shfl_xor(rs, off, 64);
      l_run[i] = l_run[i] * alpha + rs;
      m_run[i] = mnew;
#pragma unroll
      for (int j = 0; j < 4; ++j) o[i][j] *= alpha;
    }

    __syncthreads();   // everyone done reading K from KPsT
    // store P transposed: KPsT[c][r]
#pragma unroll
    for (int i = 0; i < 4; ++i)
#pragma unroll
      for (int j = 0; j < 4; ++j)
        KPsT[c0 + j][r0 + i] = p[i][j];
    __syncthreads();

    // O += P V
#pragma unroll
    for (int kk = 0; kk < 64; ++kk) {
      float4 a = *reinterpret_cast<const float4*>(&KPsT[kk][r0]);
      float4 b = *reinterpret_cast<const float4*>(&Vs[kk][c0]);
      o[0][0] += a.x * b.x; o[0][1] += a.x * b.y; o[0][2] += a.x * b.z; o[0][3] += a.x * b.w;
      o[1][0] += a.y * b.x; o[1][1] += a.y * b.y; o[1][2] += a.y * b.z; o[1][3] += a.y * b.w;
      o[2][0] += a.z * b.x; o[2][1] += a.z * b.y; o[2][2] += a.z * b.z; o[2][3] += a.z * b.w;
      o[3][0] += a.w * b.x; o[3][1] += a.w * b.y; o[3][2] += a.w * b.z; o[3][3] += a.w * b.w;
    }
  }

  // epilogue: divide by l, scatter to [b][s][h*64+d]
  const int b = bh >> 4, h = bh & 15;
#pragma unroll
  for (int i = 0; i < 4; ++i) {
    int s = q0 + r0 + i;
    float inv = 1.0f / l_run[i];
    float4 out = make_float4(o[i][0] * inv, o[i][1] * inv, o[i][2] * inv, o[i][3] * inv);
    *reinterpret_cast<float4*>(&ow[((size_t)(b * S_LEN + s)) * D_MODEL + h * DH + c0]) = out;
  }
}

// ---------------------------------------------------------------------------
extern "C" void kernel_launch(void* const* d_in, const int* in_sizes, int n_in,
                              void* d_out, int out_size, void* d_ws, size_t ws_size,
                              hipStream_t stream) {
  const float* x     = (const float*)d_in[0];   // [4,2048,1024]
  const float* w_qkv = (const float*)d_in[1];   // [3072,1024]
  const float* w_out = (const float*)d_in[2];   // [1024,1024]
  float* out = (float*)d_out;                   // [4,2048,1024]

  float* ws = (float*)d_ws;
  const size_t NQ = (size_t)BATCH * NH * S_LEN * DH;       // 8388608
  float* qw  = ws;
  float* kw  = qw + NQ;
  float* vw  = kw + NQ;
  float* ow  = vw + NQ;                                    // [b][s][1024]
  float* tab = ow + (size_t)BATCH * S_LEN * D_MODEL;       // 131072 floats

  const int M = BATCH * S_LEN;   // 8192

  rope_table_kernel<<<(S_LEN * 32 + 255) / 256, 256, 0, stream>>>(tab);

  gemm_bt<1><<<dim3(3 * D_MODEL / 64, M / 64), 256, 0, stream>>>(
      x, w_qkv, nullptr, qw, kw, vw, tab, M, 3 * D_MODEL, D_MODEL);

  attn_kernel<<<dim3(S_LEN / 64, BATCH * NH), 256, 0, stream>>>(qw, kw, vw, ow);

  gemm_bt<0><<<dim3(D_MODEL / 64, M / 64), 256, 0, stream>>>(
      ow, w_out, out, nullptr, nullptr, nullptr, tab, M, D_MODEL, D_MODEL);
}

// Round 3
// 948.056 us; speedup vs baseline: 2.3723x; 2.3723x over previous
//
#include <hip/hip_runtime.h>
#include <math.h>

#define D_MODEL 1024
#define NH      16
#define DH      64
#define S_LEN   2048
#define BATCH   4

typedef __attribute__((ext_vector_type(8))) short s8v;   // 8 bf16 (4 VGPRs)
typedef __attribute__((ext_vector_type(4))) float f4v;   // 4 f32 acc

#define MFMA(a, b, c) __builtin_amdgcn_mfma_f32_16x16x32_bf16((a), (b), (c), 0, 0, 0)

__device__ inline unsigned short f2bf(float f) {
  unsigned u = __float_as_uint(f);
  u += 0x7fffu + ((u >> 16) & 1u);          // RNE
  return (unsigned short)(u >> 16);
}
__device__ inline float bf2f(unsigned short h) {
  return __uint_as_float(((unsigned)h) << 16);
}
__device__ inline void split4(const float4 v, short4& h4, short4& l4) {
  unsigned short hx = f2bf(v.x), hy = f2bf(v.y), hz = f2bf(v.z), hw = f2bf(v.w);
  h4 = make_short4((short)hx, (short)hy, (short)hz, (short)hw);
  l4 = make_short4((short)f2bf(v.x - bf2f(hx)), (short)f2bf(v.y - bf2f(hy)),
                   (short)f2bf(v.z - bf2f(hz)), (short)f2bf(v.w - bf2f(hw)));
}

// ---------------------------------------------------------------------------
// RoPE table: tab[0:65536) = cos, tab[65536:131072) = sin, idx = s*32 + p
// ---------------------------------------------------------------------------
__global__ void rope_table_kernel(float* __restrict__ tab) {
  int i = blockIdx.x * 256 + threadIdx.x;
  if (i >= S_LEN * 32) return;
  int s = i >> 5;
  int p = i & 31;
  float invf = (float)pow(10000.0, -(double)p / 32.0);
  float ang = (float)s * invf;
  tab[i]         = cosf(ang);
  tab[65536 + i] = sinf(ang);
}

// ---------------------------------------------------------------------------
// Split-bf16 MFMA GEMM:  C[M,N] = A[M,K] * B[N,K]^T  (fp32 in/out)
// BM=BN=128, BK=32, 256 threads = 4 waves (2x2), 64x64 per wave.
// MODE 0: plain store. MODE 1: RoPE + scatter to q/k/v [b,h,s,d].
// ---------------------------------------------------------------------------
template <int MODE>
__global__ __launch_bounds__(256) void gemm_mfma(
    const float* __restrict__ A, const float* __restrict__ B,
    float* __restrict__ C,
    float* __restrict__ qw, float* __restrict__ kw, float* __restrict__ vw,
    const float* __restrict__ tab,
    int M, int N, int K)
{
  __shared__ short As[2][128][40];   // [hi/lo][row][k], pad 32->40 (2-way free)
  __shared__ short Bs[2][128][40];

  const int tid  = threadIdx.x;
  const int lane = tid & 63;
  const int wave = tid >> 6;
  const int wm = wave >> 1, wn = wave & 1;
  const int m0 = blockIdx.y * 128;
  const int n0 = blockIdx.x * 128;

  const int lr = lane & 15;
  const int lk = (lane >> 4) * 8;

  f4v acc[4][4] = {};

  float4 av[4], bv[4];
#pragma unroll
  for (int q = 0; q < 4; ++q) {           // prologue load, k0 = 0
    int f = q * 256 + tid;
    int r = f >> 3, kk = (f & 7) * 4;
    av[q] = *(const float4*)&A[(size_t)(m0 + r) * K + kk];
    bv[q] = *(const float4*)&B[(size_t)(n0 + r) * K + kk];
  }

  for (int k0 = 0; k0 < K; k0 += 32) {
    __syncthreads();                       // prev compute done reading LDS
#pragma unroll
    for (int q = 0; q < 4; ++q) {
      int f = q * 256 + tid;
      int r = f >> 3, kk = (f & 7) * 4;
      short4 h4, l4;
      split4(av[q], h4, l4);
      *(short4*)&As[0][r][kk] = h4;  *(short4*)&As[1][r][kk] = l4;
      split4(bv[q], h4, l4);
      *(short4*)&Bs[0][r][kk] = h4;  *(short4*)&Bs[1][r][kk] = l4;
    }
    __syncthreads();

    if (k0 + 32 < K) {                     // prefetch next chunk (overlaps MFMA)
#pragma unroll
      for (int q = 0; q < 4; ++q) {
        int f = q * 256 + tid;
        int r = f >> 3, kk = (f & 7) * 4;
        av[q] = *(const float4*)&A[(size_t)(m0 + r) * K + k0 + 32 + kk];
        bv[q] = *(const float4*)&B[(size_t)(n0 + r) * K + k0 + 32 + kk];
      }
    }

    s8v ah[4], al[4], bh[4], bl[4];
#pragma unroll
    for (int x = 0; x < 4; ++x) {
      ah[x] = *(const s8v*)&As[0][wm * 64 + x * 16 + lr][lk];
      al[x] = *(const s8v*)&As[1][wm * 64 + x * 16 + lr][lk];
      bh[x] = *(const s8v*)&Bs[0][wn * 64 + x * 16 + lr][lk];
      bl[x] = *(const s8v*)&Bs[1][wn * 64 + x * 16 + lr][lk];
    }
#pragma unroll
    for (int mf = 0; mf < 4; ++mf)
#pragma unroll
      for (int nf = 0; nf < 4; ++nf) {
        acc[mf][nf] = MFMA(ah[mf], bh[nf], acc[mf][nf]);
        acc[mf][nf] = MFMA(al[mf], bh[nf], acc[mf][nf]);
        acc[mf][nf] = MFMA(ah[mf], bl[nf], acc[mf][nf]);
      }
  }

  // epilogue — D layout: col = lane&15, row = (lane>>4)*4 + i
  if (MODE == 0) {
#pragma unroll
    for (int mf = 0; mf < 4; ++mf)
#pragma unroll
      for (int nf = 0; nf < 4; ++nf) {
        int c = n0 + wn * 64 + nf * 16 + lr;
#pragma unroll
        for (int i = 0; i < 4; ++i) {
          int m = m0 + wm * 64 + mf * 16 + (lane >> 4) * 4 + i;
          C[(size_t)m * N + c] = acc[mf][nf][i];
        }
      }
  } else {
#pragma unroll
    for (int nf = 0; nf < 4; ++nf) {
      int c = n0 + wn * 64 + nf * 16 + lr;     // global output feature
      int t = c >> 10;                          // 0=q 1=k 2=v
      int h = (c & 1023) >> 6;
      int d = c & 63;
#pragma unroll
      for (int mf = 0; mf < 4; ++mf)
#pragma unroll
        for (int i = 0; i < 4; ++i) {
          int m = m0 + wm * 64 + mf * 16 + (lane >> 4) * 4 + i;
          int b = m >> 11, s = m & 2047;
          float v  = acc[mf][nf][i];
          float pv = __shfl_xor(v, 1);          // partner column (c^1), same row
          size_t off = ((size_t)(b * NH + h) * S_LEN + s) * DH + d;
          if (t == 2) {
            vw[off] = v;
          } else {
            int p = d >> 1;
            float co = tab[s * 32 + p], si = tab[65536 + s * 32 + p];
            float res = ((d & 1) == 0) ? (v * co - pv * si)    // even: x1*c - x2*s
                                       : (pv * si + v * co);   // odd:  x1*s + x2*c
            ((t == 0) ? qw : kw)[off] = res;
          }
        }
    }
  }
}

// ---------------------------------------------------------------------------
// Flash attention, split-bf16 MFMA. Block = 256 thr = 4 waves; Q-tile 64 rows,
// each wave owns a 16-row stripe. K-tiles of 64. All operands hi/lo split.
// ---------------------------------------------------------------------------
__global__ __launch_bounds__(256) void attn_mfma(
    const float* __restrict__ qw, const float* __restrict__ kw,
    const float* __restrict__ vw, float* __restrict__ ow)
{
  __shared__ short Ks[2][64][72];   // [hi/lo][kv][d]
  __shared__ short Vt[2][64][72];   // [hi/lo][d][kv]  (transposed)
  __shared__ short Ps[2][64][72];   // [hi/lo][qrow][kv]
  float* Qs = (float*)&Ps[0][0][0]; // 64 x 68 fp32 staging (17408B < 18432B), used once

  const int tid  = threadIdx.x;
  const int lane = tid & 63;
  const int w    = tid >> 6;
  const int qt = blockIdx.x, bh = blockIdx.y;
  const int q0 = qt * 64;
  const size_t base = (size_t)bh * (S_LEN * DH);

  const int lr = lane & 15;
  const int lk = (lane >> 4) * 8;
  const int rg = (lane >> 4) * 4;       // row-group base (D-layout rows)

  // ---- stage Q (fp32), then extract per-wave A-fragments (hi/lo) ----
#pragma unroll
  for (int q = 0; q < 4; ++q) {
    int f = q * 256 + tid;
    int r = f >> 4, c4 = (f & 15) * 4;
    *(float4*)&Qs[r * 68 + c4] = *(const float4*)&qw[base + (size_t)(q0 + r) * DH + c4];
  }
  __syncthreads();
  s8v qh[2], ql[2];
#pragma unroll
  for (int c = 0; c < 2; ++c) {
    const float* src = &Qs[(w * 16 + lr) * 68 + c * 32 + lk];
    s8v hh, ll;
#pragma unroll
    for (int j = 0; j < 8; ++j) {
      float v = src[j];
      unsigned short h = f2bf(v);
      hh[j] = (short)h;
      ll[j] = (short)f2bf(v - bf2f(h));
    }
    qh[c] = hh; ql[c] = ll;
  }

  float m_run[4] = {-3.0e38f, -3.0e38f, -3.0e38f, -3.0e38f};
  float l_run[4] = {0.f, 0.f, 0.f, 0.f};
  f4v o[4] = {};                         // O stripe: 4 d-frags x 4 rows

  for (int kt = 0; kt <= qt; ++kt) {
    const int k0 = kt * 64;
    __syncthreads();                     // prev tile fully consumed (Q reads drained on iter 0)

    // ---- stage K (natural) + V (transposed), split hi/lo ----
#pragma unroll
    for (int q = 0; q < 4; ++q) {
      int f = q * 256 + tid;
      int r = f >> 4, c4 = (f & 15) * 4;
      float4 kv4 = *(const float4*)&kw[base + (size_t)(k0 + r) * DH + c4];
      short4 h4, l4;
      split4(kv4, h4, l4);
      *(short4*)&Ks[0][r][c4] = h4;  *(short4*)&Ks[1][r][c4] = l4;
      float4 vv = *(const float4*)&vw[base + (size_t)(k0 + r) * DH + c4];
      split4(vv, h4, l4);
      Vt[0][c4 + 0][r] = h4.x; Vt[1][c4 + 0][r] = l4.x;
      Vt[0][c4 + 1][r] = h4.y; Vt[1][c4 + 1][r] = l4.y;
      Vt[0][c4 + 2][r] = h4.z; Vt[1][c4 + 2][r] = l4.z;
      Vt[0][c4 + 3][r] = h4.w; Vt[1][c4 + 3][r] = l4.w;
    }
    __syncthreads();

    // ---- S = Q K^T (per-wave 16x64 stripe) ----
    f4v sf[4] = {};
#pragma unroll
    for (int f = 0; f < 4; ++f)
#pragma unroll
      for (int c = 0; c < 2; ++c) {
        s8v kbh = *(const s8v*)&Ks[0][f * 16 + lr][c * 32 + lk];
        s8v kbl = *(const s8v*)&Ks[1][f * 16 + lr][c * 32 + lk];
        sf[f] = MFMA(qh[c], kbh, sf[f]);
        sf[f] = MFMA(ql[c], kbh, sf[f]);
        sf[f] = MFMA(qh[c], kbl, sf[f]);
      }

    // ---- scale + causal mask + online softmax ----
    const bool diag = (kt == qt);
    float p[4][4];                        // [f][i]
    float sc[4][4];
#pragma unroll
    for (int f = 0; f < 4; ++f)
#pragma unroll
      for (int i = 0; i < 4; ++i) {
        float v = sf[f][i] * 0.125f;
        if (diag) {
          int col = f * 16 + lr;          // kv within tile
          int row = rg + i + w * 16;      // q within tile (k0 == q0 here)
          if (col > row) v = -3.0e38f;
        }
        sc[f][i] = v;
      }
#pragma unroll
    for (int i = 0; i < 4; ++i) {
      float mx = fmaxf(fmaxf(sc[0][i], sc[1][i]), fmaxf(sc[2][i], sc[3][i]));
#pragma unroll
      for (int off = 1; off < 16; off <<= 1) mx = fmaxf(mx, __shfl_xor(mx, off));
      float mnew  = fmaxf(m_run[i], mx);
      float alpha = __expf(m_run[i] - mnew);
      float rs = 0.f;
#pragma unroll
      for (int f = 0; f < 4; ++f) { p[f][i] = __expf(sc[f][i] - mnew); rs += p[f][i]; }
#pragma unroll
      for (int off = 1; off < 16; off <<= 1) rs += __shfl_xor(rs, off);
      l_run[i] = l_run[i] * alpha + rs;
      m_run[i] = mnew;
#pragma unroll
      for (int f2 = 0; f2 < 4; ++f2) o[f2][i] *= alpha;
    }

    // ---- write P (hi/lo) to wave-private LDS rows ----
#pragma unroll
    for (int f = 0; f < 4; ++f)
#pragma unroll
      for (int i = 0; i < 4; ++i) {
        int row = w * 16 + rg + i, col = f * 16 + lr;
        unsigned short h = f2bf(p[f][i]);
        Ps[0][row][col] = (short)h;
        Ps[1][row][col] = (short)f2bf(p[f][i] - bf2f(h));
      }
    asm volatile("s_waitcnt lgkmcnt(0)" ::: "memory");   // wave-local write->read fence
    __builtin_amdgcn_sched_barrier(0);                   // rule #18: block MFMA hoisting

    // ---- O += P V ----
#pragma unroll
    for (int c = 0; c < 2; ++c) {
      s8v pah = *(const s8v*)&Ps[0][w * 16 + lr][c * 32 + lk];
      s8v pal = *(const s8v*)&Ps[1][w * 16 + lr][c * 32 + lk];
#pragma unroll
      for (int f2 = 0; f2 < 4; ++f2) {
        s8v vbh = *(const s8v*)&Vt[0][f2 * 16 + lr][c * 32 + lk];
        s8v vbl = *(const s8v*)&Vt[1][f2 * 16 + lr][c * 32 + lk];
        o[f2] = MFMA(pah, vbh, o[f2]);
        o[f2] = MFMA(pal, vbh, o[f2]);
        o[f2] = MFMA(pah, vbl, o[f2]);
      }
    }
  }

  // ---- epilogue: divide by l, scatter to [b][s][h*64+d] ----
  const int b = bh >> 4, h = bh & 15;
#pragma unroll
  for (int i = 0; i < 4; ++i) {
    int s = q0 + w * 16 + rg + i;
    float inv = 1.0f / l_run[i];
#pragma unroll
    for (int f2 = 0; f2 < 4; ++f2) {
      int d = f2 * 16 + lr;
      ow[((size_t)(b * S_LEN + s)) * D_MODEL + h * DH + d] = o[f2][i] * inv;
    }
  }
}

// ---------------------------------------------------------------------------
extern "C" void kernel_launch(void* const* d_in, const int* in_sizes, int n_in,
                              void* d_out, int out_size, void* d_ws, size_t ws_size,
                              hipStream_t stream) {
  const float* x     = (const float*)d_in[0];
  const float* w_qkv = (const float*)d_in[1];
  const float* w_out = (const float*)d_in[2];
  float* out = (float*)d_out;

  float* ws = (float*)d_ws;
  const size_t NQ = (size_t)BATCH * NH * S_LEN * DH;
  float* qw  = ws;
  float* kw  = qw + NQ;
  float* vw  = kw + NQ;
  float* ow  = vw + NQ;
  float* tab = ow + (size_t)BATCH * S_LEN * D_MODEL;

  const int M = BATCH * S_LEN;   // 8192

  rope_table_kernel<<<(S_LEN * 32 + 255) / 256, 256, 0, stream>>>(tab);

  gemm_mfma<1><<<dim3(3 * D_MODEL / 128, M / 128), 256, 0, stream>>>(
      x, w_qkv, nullptr, qw, kw, vw, tab, M, 3 * D_MODEL, D_MODEL);

  attn_mfma<<<dim3(S_LEN / 64, BATCH * NH), 256, 0, stream>>>(qw, kw, vw, ow);

  gemm_mfma<0><<<dim3(D_MODEL / 128, M / 128), 256, 0, stream>>>(
      ow, w_out, out, nullptr, nullptr, nullptr, tab, M, D_MODEL, D_MODEL);
}